// Round 2
// baseline (2422.219 us; speedup 1.0000x reference)
//
#include <hip/hip_runtime.h>
#include <hip/hip_bf16.h>

// Decoder (EGNN-style) on MI355X. All float tensors are fp32 (per reference);
// output fp32. Structure per call:
//   k_g, k_hinit, k_count, k_scan, k_bucket,
//   4x { k_nodeA (A1/A2/hn pre-GEMMs), k_edge (CSR per-node edge MLP, no atomics),
//        k_node (node MLP + LayerNorm) },
//   k_out.
// Key ideas: edge-input GEMM hoisted to nodes (A1/A2), per-node blocks kill the
// scatter, LDS weights read with wave-uniform (broadcast) addresses, r1 in VGPRs.

namespace {

constexpr int kB = 16, kN = 1024, kH = 64, kE = 32768, kLat = 128;

__device__ __forceinline__ unsigned short f2bf(float f){
  union { float f; unsigned int u; } v; v.f = f;
  unsigned int r = v.u + 0x7fffu + ((v.u >> 16) & 1u);
  return (unsigned short)(r >> 16);
}
__device__ __forceinline__ float bfu2f(unsigned short u){
  union { unsigned int u; float f; } v; v.u = ((unsigned int)u) << 16; return v.f;
}
__device__ __forceinline__ float siluf(float x){ return x / (1.0f + __expf(-x)); }

// ---- g = z @ Wg + bg : (16,64) --------------------------------------------
__global__ void k_g(const float* z, const float* Wg, const float* bg, float* g){
  int t = blockIdx.x*256 + threadIdx.x;      // 1024 threads
  int b = t >> 6, j = t & 63;
  float acc = bg[j];
  for (int k = 0; k < kLat; k++) acc += z[b*kLat+k] * Wg[k*64+j];
  g[t] = acc;
}

// ---- h init + zero posA + zero cntI ---------------------------------------
__global__ void k_hinit(const float* nf, const float* Wn, const float* bn,
                        const float* g, float* h, float* posA, int* cntI){
  int idx = blockIdx.x*256 + threadIdx.x;    // B*N*H = 1048576 exactly
  int b = idx >> 16, rem = idx & 65535, n = rem >> 6, j = rem & 63;
  float acc = bn[j] + g[b*64 + j];
  #pragma unroll
  for (int k = 0; k < 3; k++) acc += nf[n*3+k] * Wn[k*64+j];
  h[idx] = acc;
  if (idx < kN*kB*3) posA[idx] = 0.0f;
  if (idx < kN)      cntI[idx] = 0;
}

// ---- CSR build -------------------------------------------------------------
__global__ void k_count(const int* ei, int* cntI){
  int e = blockIdx.x*256 + threadIdx.x;      // E exactly
  atomicAdd(&cntI[ei[e]], 1);
}

__global__ void k_scan(const int* cntI, int* off, int* fill, float* cntF){
  __shared__ int s0[1024];
  __shared__ int s1[1024];
  int t = threadIdx.x;
  int c = cntI[t];
  s0[t] = c; __syncthreads();
  int* src = s0; int* dst = s1;
  for (int o = 1; o < 1024; o <<= 1){
    int v = src[t] + ((t >= o) ? src[t-o] : 0);
    dst[t] = v; __syncthreads();
    int* tmp = src; src = dst; dst = tmp;
  }
  int inc = src[t];
  off[t] = inc - c;               // exclusive
  if (t == 1023) off[1024] = inc;
  fill[t] = 0;
  cntF[t] = (float)(c > 0 ? c : 1);
}

__global__ void k_bucket(const int* ei, const int* off, int* fill, int* ecol){
  int e = blockIdx.x*256 + threadIdx.x;
  int r = ei[e];
  int s = atomicAdd(&fill[r], 1);
  ecol[off[r] + s] = ei[kE + e];
}

// ---- per-layer node pre-GEMMs: A1 = h@eW1[:64]+eb1, A2 = h@eW1[64:128],
// ----                          hn = h@nW1[:64]+nb1.  A1/A2 stored [n][b][64].
__global__ __launch_bounds__(256) void k_nodeA(const float* h, const float* eW1,
                                               const float* eb1_, const float* nW1,
                                               const float* nb1_, int l,
                                               float* A1t, float* A2t, float* hn){
  __shared__ __align__(16) float Wa[4096];
  __shared__ __align__(16) float Wb[4096];
  __shared__ __align__(16) float Wc[4096];
  __shared__ float eb1s[64], nb1s[64];
  int tid = threadIdx.x;
  const float4* e1a = (const float4*)(eW1 + l*8256);        // rows 0..63
  const float4* e1b = (const float4*)(eW1 + l*8256 + 4096); // rows 64..127
  const float4* n1  = (const float4*)(nW1 + l*8192);        // rows 0..63
  for (int i = tid; i < 1024; i += 256){
    ((float4*)Wa)[i] = e1a[i]; ((float4*)Wb)[i] = e1b[i]; ((float4*)Wc)[i] = n1[i];
  }
  if (tid < 64){ eb1s[tid] = eb1_[l*64+tid]; nb1s[tid] = nb1_[l*64+tid]; }
  __syncthreads();
  int rl = tid >> 2, q = tid & 3;
  int row = blockIdx.x*64 + rl;    // row = b*N + n
  int b = row >> 10, n = row & 1023;
  float hr[64];
  const float4* hp = (const float4*)(h + row*64);
  #pragma unroll
  for (int k4 = 0; k4 < 16; k4++){
    float4 v = hp[k4];
    hr[4*k4] = v.x; hr[4*k4+1] = v.y; hr[4*k4+2] = v.z; hr[4*k4+3] = v.w;
  }
  int tb = (n*16 + b)*64;
  for (int jc = 0; jc < 4; jc++){
    int j0 = q*16 + jc*4;
    float a1x=eb1s[j0], a1y=eb1s[j0+1], a1z=eb1s[j0+2], a1w=eb1s[j0+3];
    float a2x=0.f, a2y=0.f, a2z=0.f, a2w=0.f;
    float a3x=nb1s[j0], a3y=nb1s[j0+1], a3z=nb1s[j0+2], a3w=nb1s[j0+3];
    #pragma unroll
    for (int k = 0; k < 64; k++){
      float hv = hr[k];
      float4 w1 = *(const float4*)(Wa + k*64 + j0);
      float4 w2 = *(const float4*)(Wb + k*64 + j0);
      float4 w3 = *(const float4*)(Wc + k*64 + j0);
      a1x += hv*w1.x; a1y += hv*w1.y; a1z += hv*w1.z; a1w += hv*w1.w;
      a2x += hv*w2.x; a2y += hv*w2.y; a2z += hv*w2.z; a2w += hv*w2.w;
      a3x += hv*w3.x; a3y += hv*w3.y; a3z += hv*w3.z; a3w += hv*w3.w;
    }
    float4 o1 = {a1x,a1y,a1z,a1w};
    float4 o2 = {a2x,a2y,a2z,a2w};
    float4 o3 = {a3x,a3y,a3z,a3w};
    *(float4*)(A1t + tb + j0) = o1;
    *(float4*)(A2t + tb + j0) = o2;
    *(float4*)(hn + row*64 + j0) = o3;
  }
}

// ---- the hot kernel: one block per node r, 256 thr = 16 edges x 16 batches.
__global__ __launch_bounds__(256, 2) void k_edge(const float* A1t, const float* A2t,
      const float* eW1, const float* eW2, const float* eb2_, const float* cW1,
      const float* cb1_, const float* cW2_, int l,
      const int* off, const int* ecol, const float* cntF,
      const float* posIn, float* posOut, float* aggT){
  __shared__ __align__(16) float W2s[4096];            // eW2[l], [k][j]
  __shared__ __align__(16) float W1s[4096];            // cW1[l], [k][j]
  __shared__ __align__(16) unsigned short mlds[256*68];// per-thread m spill (bf16)
  __shared__ __align__(16) float A1s[16*68];           // A1 rows of node r, pad 68
  __shared__ float aggS[16*68];                        // agg accumulator, pad 68
  __shared__ float posS[64];                           // pos delta accumulator
  __shared__ float posR[64];                           // pos of node r
  __shared__ __align__(16) float w1d[64];              // eW1[l][128][:] (d2 row)
  __shared__ float eb2s[64], cb1s[64], cW2s[64];

  int tid = threadIdx.x;
  int r = blockIdx.x;
  int eL = tid >> 4, b = tid & 15;

  {
    const float4* w2p = (const float4*)(eW2 + l*4096);
    const float4* w1p = (const float4*)(cW1 + l*4096);
    for (int i = tid; i < 1024; i += 256){
      ((float4*)W2s)[i] = w2p[i]; ((float4*)W1s)[i] = w1p[i];
    }
  }
  if (tid < 64){
    w1d[tid]  = eW1[l*8256 + 8192 + tid];
    eb2s[tid] = eb2_[l*64+tid];
    cb1s[tid] = cb1_[l*64+tid];
    cW2s[tid] = cW2_[l*64+tid];
  }
  {
    float4 v = *(const float4*)(A1t + r*1024 + tid*4);
    *(float4*)(A1s + (tid>>4)*68 + (tid&15)*4) = v;
  }
  for (int i = tid; i < 16*68; i += 256) aggS[i] = 0.0f;
  if (tid < 64){
    posS[tid] = 0.0f;
    int pb = tid >> 2, pk = tid & 3;
    posR[tid] = (pk < 3) ? posIn[r*48 + pb*3 + pk] : 0.0f;
  }
  __syncthreads();

  int e0  = off[r];
  int cnt = off[r+1] - e0;
  int mbase = tid*68;
  float prx = posR[b*4+0], pry = posR[b*4+1], prz = posR[b*4+2];

  for (int es = 0; es < cnt; es += 16){
    int eidx = es + eL;
    bool valid = eidx < cnt;
    int c = valid ? ecol[e0 + eidx] : r;
    float dx = prx - posIn[c*48 + b*3 + 0];
    float dy = pry - posIn[c*48 + b*3 + 1];
    float dz = prz - posIn[c*48 + b*3 + 2];
    float d2 = dx*dx + dy*dy + dz*dz;

    // r1 = silu(A1[r] + A2[c] + d2*w1d)  (64 regs, k fully unrolled)
    float r1[64];
    const float4* a2p = (const float4*)(A2t + c*1024 + b*64);
    #pragma unroll
    for (int k4 = 0; k4 < 16; k4++){
      float4 v = a2p[k4];
      const float4 a1v = *(const float4*)(A1s + b*68 + k4*4);
      const float4 w1v = *(const float4*)(w1d + k4*4);
      r1[4*k4+0] = siluf(v.x + a1v.x + d2*w1v.x);
      r1[4*k4+1] = siluf(v.y + a1v.y + d2*w1v.y);
      r1[4*k4+2] = siluf(v.z + a1v.z + d2*w1v.z);
      r1[4*k4+3] = siluf(v.w + a1v.w + d2*w1v.w);
    }

    // stage 1: m = silu(r1 @ eW2 + eb2); W reads are wave-uniform (broadcast)
    for (int jc = 0; jc < 16; jc++){
      int j0 = jc*4;
      float ax=eb2s[j0], ay=eb2s[j0+1], az=eb2s[j0+2], aw=eb2s[j0+3];
      #pragma unroll
      for (int k = 0; k < 64; k++){
        const float4 w4 = *(const float4*)(W2s + k*64 + j0);
        float rv = r1[k];
        ax += rv*w4.x; ay += rv*w4.y; az += rv*w4.z; aw += rv*w4.w;
      }
      ax = siluf(ax); ay = siluf(ay); az = siluf(az); aw = siluf(aw);
      unsigned short* mp = mlds + mbase + j0;
      mp[0] = f2bf(ax); mp[1] = f2bf(ay); mp[2] = f2bf(az); mp[3] = f2bf(aw);
      if (valid){  // agg accumulates the exact fp32 values
        __hip_atomic_fetch_add(&aggS[b*68+j0+0], ax, __ATOMIC_RELAXED, __HIP_MEMORY_SCOPE_WORKGROUP);
        __hip_atomic_fetch_add(&aggS[b*68+j0+1], ay, __ATOMIC_RELAXED, __HIP_MEMORY_SCOPE_WORKGROUP);
        __hip_atomic_fetch_add(&aggS[b*68+j0+2], az, __ATOMIC_RELAXED, __HIP_MEMORY_SCOPE_WORKGROUP);
        __hip_atomic_fetch_add(&aggS[b*68+j0+3], aw, __ATOMIC_RELAXED, __HIP_MEMORY_SCOPE_WORKGROUP);
      }
    }

    // stage 2: w = silu(m @ cW1 + cb1) . cW2   (bf16 m: error only feeds pos,
    // which is exactly 0 in this problem, so output impact ~0)
    float wv = 0.0f;
    for (int jc = 0; jc < 16; jc++){
      int j0 = jc*4;
      float ax=cb1s[j0], ay=cb1s[j0+1], az=cb1s[j0+2], aw=cb1s[j0+3];
      #pragma unroll
      for (int k4 = 0; k4 < 16; k4++){
        const ushort4 mu = *(const ushort4*)(mlds + mbase + k4*4);
        float m0=bfu2f(mu.x), m1=bfu2f(mu.y), m2=bfu2f(mu.z), m3=bfu2f(mu.w);
        const float4 wA = *(const float4*)(W1s + (k4*4+0)*64 + j0);
        const float4 wB = *(const float4*)(W1s + (k4*4+1)*64 + j0);
        const float4 wC = *(const float4*)(W1s + (k4*4+2)*64 + j0);
        const float4 wD = *(const float4*)(W1s + (k4*4+3)*64 + j0);
        ax += m0*wA.x + m1*wB.x + m2*wC.x + m3*wD.x;
        ay += m0*wA.y + m1*wB.y + m2*wC.y + m3*wD.y;
        az += m0*wA.z + m1*wB.z + m2*wC.z + m3*wD.z;
        aw += m0*wA.w + m1*wB.w + m2*wC.w + m3*wD.w;
      }
      ax = siluf(ax); ay = siluf(ay); az = siluf(az); aw = siluf(aw);
      wv += ax*cW2s[j0] + ay*cW2s[j0+1] + az*cW2s[j0+2] + aw*cW2s[j0+3];
    }

    if (valid){
      __hip_atomic_fetch_add(&posS[b*4+0], dx*wv, __ATOMIC_RELAXED, __HIP_MEMORY_SCOPE_WORKGROUP);
      __hip_atomic_fetch_add(&posS[b*4+1], dy*wv, __ATOMIC_RELAXED, __HIP_MEMORY_SCOPE_WORKGROUP);
      __hip_atomic_fetch_add(&posS[b*4+2], dz*wv, __ATOMIC_RELAXED, __HIP_MEMORY_SCOPE_WORKGROUP);
    }
  }
  __syncthreads();
  {
    int bb = tid >> 4, j0 = (tid & 15)*4;
    float4 v = { aggS[bb*68+j0], aggS[bb*68+j0+1], aggS[bb*68+j0+2], aggS[bb*68+j0+3] };
    *(float4*)(aggT + r*1024 + tid*4) = v;
  }
  if (tid < 64){
    int pb = tid >> 2, pk = tid & 3;
    if (pk < 3)
      posOut[r*48 + pb*3 + pk] = posR[pb*4+pk] + posS[pb*4+pk] / cntF[r];
  }
}

// ---- node MLP + residual + LayerNorm --------------------------------------
__global__ __launch_bounds__(256) void k_node(float* h, const float* hn, const float* aggT,
      const float* nW1, const float* nW2, const float* nb2_,
      const float* lng_, const float* lnb_, int l){
  __shared__ __align__(16) float W1b[4096];   // nW1[l][64:128]
  __shared__ __align__(16) float W2s[4096];   // nW2[l]
  __shared__ __align__(16) float tl[64*68];
  __shared__ float nb2s[64], lngs[64], lnbs[64];
  int tid = threadIdx.x;
  {
    const float4* n1 = (const float4*)(nW1 + l*8192 + 4096);
    const float4* n2 = (const float4*)(nW2 + l*4096);
    for (int i = tid; i < 1024; i += 256){ ((float4*)W1b)[i] = n1[i]; ((float4*)W2s)[i] = n2[i]; }
  }
  if (tid < 64){
    nb2s[tid] = nb2_[l*64+tid];
    lngs[tid] = lng_[l*64+tid];
    lnbs[tid] = lnb_[l*64+tid];
  }
  __syncthreads();
  int rl = tid >> 2, q = tid & 3;
  int row = blockIdx.x*64 + rl;
  int b = row >> 10, n = row & 1023;
  float ag[64];
  const float4* ap = (const float4*)(aggT + (n*16 + b)*64);
  #pragma unroll
  for (int k4 = 0; k4 < 16; k4++){
    float4 v = ap[k4];
    ag[4*k4] = v.x; ag[4*k4+1] = v.y; ag[4*k4+2] = v.z; ag[4*k4+3] = v.w;
  }
  for (int jc = 0; jc < 4; jc++){
    int j0 = q*16 + jc*4;
    float4 acc = *(const float4*)(hn + row*64 + j0);
    #pragma unroll
    for (int k = 0; k < 64; k++){
      const float4 w = *(const float4*)(W1b + k*64 + j0);
      float a = ag[k];
      acc.x += a*w.x; acc.y += a*w.y; acc.z += a*w.z; acc.w += a*w.w;
    }
    float4 t4 = { siluf(acc.x), siluf(acc.y), siluf(acc.z), siluf(acc.w) };
    *(float4*)(tl + rl*68 + j0) = t4;
  }
  __syncthreads();
  float tr[64];
  #pragma unroll
  for (int k4 = 0; k4 < 16; k4++){
    float4 v = *(const float4*)(tl + rl*68 + k4*4);
    tr[4*k4] = v.x; tr[4*k4+1] = v.y; tr[4*k4+2] = v.z; tr[4*k4+3] = v.w;
  }
  float hv[16];
  #pragma unroll
  for (int jc = 0; jc < 4; jc++){
    int j0 = q*16 + jc*4;
    float ax=nb2s[j0], ay=nb2s[j0+1], az=nb2s[j0+2], aw=nb2s[j0+3];
    #pragma unroll
    for (int k = 0; k < 64; k++){
      const float4 w = *(const float4*)(W2s + k*64 + j0);
      float t = tr[k];
      ax += t*w.x; ay += t*w.y; az += t*w.z; aw += t*w.w;
    }
    const float4 ho = *(const float4*)(h + row*64 + j0);
    hv[4*jc+0] = ho.x + ax; hv[4*jc+1] = ho.y + ay;
    hv[4*jc+2] = ho.z + az; hv[4*jc+3] = ho.w + aw;
  }
  float s1 = 0.f, s2 = 0.f;
  #pragma unroll
  for (int i = 0; i < 16; i++){ s1 += hv[i]; s2 += hv[i]*hv[i]; }
  s1 += __shfl_xor(s1, 1, 64); s1 += __shfl_xor(s1, 2, 64);
  s2 += __shfl_xor(s2, 1, 64); s2 += __shfl_xor(s2, 2, 64);
  float mu  = s1 * (1.0f/64.0f);
  float var = s2 * (1.0f/64.0f) - mu*mu;
  float rs  = rsqrtf(var + 1e-5f);
  #pragma unroll
  for (int jc = 0; jc < 4; jc++){
    int j0 = q*16 + jc*4;
    float4 o;
    o.x = (hv[4*jc+0]-mu)*rs*lngs[j0+0] + lnbs[j0+0];
    o.y = (hv[4*jc+1]-mu)*rs*lngs[j0+1] + lnbs[j0+1];
    o.z = (hv[4*jc+2]-mu)*rs*lngs[j0+2] + lnbs[j0+2];
    o.w = (hv[4*jc+3]-mu)*rs*lngs[j0+3] + lnbs[j0+3];
    *(float4*)(h + row*64 + j0) = o;
  }
}

// ---- output head -----------------------------------------------------------
__global__ __launch_bounds__(256) void k_out(const float* h, const float* oW1,
                                             const float* ob1_, const float* oW2,
                                             const float* ob2_, float* out){
  __shared__ __align__(16) float W1[4096];
  __shared__ __align__(16) float tl[64*68];
  __shared__ float W2[192];
  __shared__ float ob1s[64];
  __shared__ float ob2s[3];
  int tid = threadIdx.x;
  {
    const float4* w1p = (const float4*)oW1;
    for (int i = tid; i < 1024; i += 256) ((float4*)W1)[i] = w1p[i];
  }
  if (tid < 192) W2[tid] = oW2[tid];
  if (tid < 64)  ob1s[tid] = ob1_[tid];
  if (tid < 3)   ob2s[tid] = ob2_[tid];
  __syncthreads();
  int rl = tid >> 2, q = tid & 3;
  int row = blockIdx.x*64 + rl;
  float hr[64];
  const float4* hp = (const float4*)(h + row*64);
  #pragma unroll
  for (int k4 = 0; k4 < 16; k4++){
    float4 v = hp[k4];
    hr[4*k4] = v.x; hr[4*k4+1] = v.y; hr[4*k4+2] = v.z; hr[4*k4+3] = v.w;
  }
  for (int jc = 0; jc < 4; jc++){
    int j0 = q*16 + jc*4;
    float ax=ob1s[j0], ay=ob1s[j0+1], az=ob1s[j0+2], aw=ob1s[j0+3];
    #pragma unroll
    for (int k = 0; k < 64; k++){
      const float4 w = *(const float4*)(W1 + k*64 + j0);
      float hvv = hr[k];
      ax += hvv*w.x; ay += hvv*w.y; az += hvv*w.z; aw += hvv*w.w;
    }
    float4 t4 = { fmaxf(ax,0.f), fmaxf(ay,0.f), fmaxf(az,0.f), fmaxf(aw,0.f) };
    *(float4*)(tl + rl*68 + j0) = t4;
  }
  __syncthreads();
  if (q < 3){
    float acc = ob2s[q];
    #pragma unroll
    for (int k = 0; k < 64; k++) acc += tl[rl*68 + k] * W2[k*3 + q];
    int b = row >> 10, n = row & 1023;
    out[b*3072 + n*3 + q] = acc;
  }
}

} // namespace

extern "C" void kernel_launch(void* const* d_in, const int* in_sizes, int n_in,
                              void* d_out, int out_size, void* d_ws, size_t ws_size,
                              hipStream_t stream){
  const float* z   = (const float*)d_in[0];
  const int*   ei  = (const int*)d_in[1];
  const float* nf  = (const float*)d_in[2];
  const float* Wg  = (const float*)d_in[3];  const float* bg  = (const float*)d_in[4];
  const float* Wn  = (const float*)d_in[5];  const float* bn  = (const float*)d_in[6];
  const float* eW1 = (const float*)d_in[7];  const float* eb1 = (const float*)d_in[8];
  const float* eW2 = (const float*)d_in[9];  const float* eb2 = (const float*)d_in[10];
  const float* cW1 = (const float*)d_in[11]; const float* cb1 = (const float*)d_in[12];
  const float* cW2 = (const float*)d_in[13];
  const float* nW1 = (const float*)d_in[14]; const float* nb1 = (const float*)d_in[15];
  const float* nW2 = (const float*)d_in[16]; const float* nb2 = (const float*)d_in[17];
  const float* lng = (const float*)d_in[18]; const float* lnb = (const float*)d_in[19];
  const float* oW1 = (const float*)d_in[20]; const float* ob1 = (const float*)d_in[21];
  const float* oW2 = (const float*)d_in[22]; const float* ob2 = (const float*)d_in[23];

  float* W     = (float*)d_ws;
  float* h     = W;                    // [B*N][64]
  float* A1t   = W + 1048576;          // [N][B][64]
  float* A2t   = W + 2097152;          // [N][B][64]
  float* hn    = W + 3145728;          // [B*N][64]
  float* aggT  = W + 4194304;          // [N][B][64]
  float* posA  = W + 5242880;          // [N][B][3]
  float* posB  = W + 5292032;
  float* g     = W + 5341184;          // [B][64]
  float* cntF  = W + 5342208;          // [N]
  int*   cntI  = (int*)(W + 5343232);  // [N]
  int*   off   = cntI + 1024;          // [N+1]
  int*   fill  = off + 1025;           // [N]
  int*   ecol  = fill + 1024;          // [E] (+pad)

  k_g     <<<4,    256, 0, stream>>>(z, Wg, bg, g);
  k_hinit <<<4096, 256, 0, stream>>>(nf, Wn, bn, g, h, posA, cntI);
  k_count <<<128,  256, 0, stream>>>(ei, cntI);
  k_scan  <<<1,   1024, 0, stream>>>(cntI, off, fill, cntF);
  k_bucket<<<128,  256, 0, stream>>>(ei, off, fill, ecol);

  for (int l = 0; l < 4; l++){
    float* pin  = (l & 1) ? posB : posA;
    float* pout = (l & 1) ? posA : posB;
    k_nodeA<<<256, 256, 0, stream>>>(h, eW1, eb1, nW1, nb1, l, A1t, A2t, hn);
    k_edge <<<1024,256, 0, stream>>>(A1t, A2t, eW1, eW2, eb2, cW1, cb1, cW2, l,
                                     off, ecol, cntF, pin, pout, aggT);
    k_node <<<256, 256, 0, stream>>>(h, hn, aggT, nW1, nW2, nb2, lng, lnb, l);
  }
  k_out<<<256, 256, 0, stream>>>(h, oW1, ob1, oW2, ob2, (float*)d_out);
}

// Round 3
// 472.753 us; speedup vs baseline: 5.1236x; 5.1236x over previous
//
#include <hip/hip_runtime.h>
#include <hip/hip_bf16.h>

// Decoder (EGNN-style) on MI355X.
// Key identity: pos starts at 0 => diff=0 => trans=0 => pos stays 0 forever.
// So d2==0, stage-2 (cW1/cW2/counts/pos) is dead code. Edge MLP reduces to
//   m = silu( silu(A1[r,b] + A2[c,b]) @ eW2 + eb2 ),  agg[r,b] = sum_e m.
// k_edge: one block per node r, 4 waves; one wave per edge (16 batches = MFMA
// N-dim). r1 built straight into bf16 B-fragments (no per-thread k arrays ->
// no scratch spill, which was round-2's 174MB WRITE_SIZE problem).

namespace {

constexpr int kB = 16, kN = 1024, kH = 64, kE = 32768, kLat = 128;

typedef __attribute__((ext_vector_type(8))) short short8;   // 8 bf16 (4 VGPRs)
typedef __attribute__((ext_vector_type(4))) float floatx4;

__device__ __forceinline__ unsigned short f2bf(float f){
  union { float f; unsigned int u; } v; v.f = f;
  unsigned int r = v.u + 0x7fffu + ((v.u >> 16) & 1u);
  return (unsigned short)(r >> 16);
}
__device__ __forceinline__ float bflo(unsigned int u){
  union { unsigned int u; float f; } v; v.u = u << 16; return v.f;
}
__device__ __forceinline__ float bfhi(unsigned int u){
  union { unsigned int u; float f; } v; v.u = u & 0xffff0000u; return v.f;
}
__device__ __forceinline__ unsigned int packbf(float a, float b){
  return ((unsigned int)f2bf(b) << 16) | (unsigned int)f2bf(a);
}
__device__ __forceinline__ float siluf(float x){ return x / (1.0f + __expf(-x)); }

// ---- g = z @ Wg + bg : (16,64) --------------------------------------------
__global__ void k_g(const float* z, const float* Wg, const float* bg, float* g){
  int t = blockIdx.x*256 + threadIdx.x;      // 1024 threads
  int b = t >> 6, j = t & 63;
  float acc = bg[j];
  for (int k = 0; k < kLat; k++) acc += z[b*kLat+k] * Wg[k*64+j];
  g[t] = acc;
}

// ---- h init + zero cntI ----------------------------------------------------
__global__ void k_hinit(const float* nf, const float* Wn, const float* bn,
                        const float* g, float* h, int* cntI){
  int idx = blockIdx.x*256 + threadIdx.x;    // B*N*H = 1048576 exactly
  int b = idx >> 16, rem = idx & 65535, n = rem >> 6, j = rem & 63;
  float acc = bn[j] + g[b*64 + j];
  #pragma unroll
  for (int k = 0; k < 3; k++) acc += nf[n*3+k] * Wn[k*64+j];
  h[idx] = acc;
  if (idx < kN) cntI[idx] = 0;
}

// ---- CSR build -------------------------------------------------------------
__global__ void k_count(const int* ei, int* cntI){
  int e = blockIdx.x*256 + threadIdx.x;      // E exactly
  atomicAdd(&cntI[ei[e]], 1);
}

__global__ void k_scan(const int* cntI, int* off, int* fill){
  __shared__ int s0[1024];
  __shared__ int s1[1024];
  int t = threadIdx.x;
  int c = cntI[t];
  s0[t] = c; __syncthreads();
  int* src = s0; int* dst = s1;
  for (int o = 1; o < 1024; o <<= 1){
    int v = src[t] + ((t >= o) ? src[t-o] : 0);
    dst[t] = v; __syncthreads();
    int* tmp = src; src = dst; dst = tmp;
  }
  int inc = src[t];
  off[t] = inc - c;               // exclusive
  if (t == 1023) off[1024] = inc;
  fill[t] = 0;
}

__global__ void k_bucket(const int* ei, const int* off, int* fill, int* ecol){
  int e = blockIdx.x*256 + threadIdx.x;
  int r = ei[e];
  int s = atomicAdd(&fill[r], 1);
  ecol[off[r] + s] = ei[kE + e];
}

// ---- eW2 -> bf16 A-operand fragments, exact lane order ---------------------
// wfragE[l][f][lane][j8], f = jt*2+ks: A[m=lane&15 -> j][k=quad*8+j8 (+32ks)]
__global__ void k_wfrag(const float* eW2, unsigned short* wfragE){
  int l = blockIdx.x;
  for (int i = threadIdx.x; i < 4096; i += 256){
    int f = i >> 9, lane = (i >> 3) & 63, j8 = i & 7;
    int jt = f >> 1, ks = f & 1;
    int k = ks*32 + (lane >> 4)*8 + j8;
    int j = jt*16 + (lane & 15);
    wfragE[l*4096 + i] = f2bf(eW2[l*4096 + k*64 + j]);
  }
}

// ---- per-layer node pre-GEMMs: A1 = h@eW1[:64]+eb1 (fp32),
// ----   A2 = h@eW1[64:128] (bf16), hn = h@nW1[:64]+nb1.  [n][b][64] layout.
__global__ __launch_bounds__(256) void k_nodeA(const float* h, const float* eW1,
                                               const float* eb1_, const float* nW1,
                                               const float* nb1_, int l,
                                               float* A1t, unsigned short* A2bf,
                                               float* hn){
  __shared__ __align__(16) float Wa[4096];
  __shared__ __align__(16) float Wb[4096];
  __shared__ __align__(16) float Wc[4096];
  __shared__ float eb1s[64], nb1s[64];
  int tid = threadIdx.x;
  const float4* e1a = (const float4*)(eW1 + l*8256);        // rows 0..63
  const float4* e1b = (const float4*)(eW1 + l*8256 + 4096); // rows 64..127
  const float4* n1  = (const float4*)(nW1 + l*8192);        // rows 0..63
  for (int i = tid; i < 1024; i += 256){
    ((float4*)Wa)[i] = e1a[i]; ((float4*)Wb)[i] = e1b[i]; ((float4*)Wc)[i] = n1[i];
  }
  if (tid < 64){ eb1s[tid] = eb1_[l*64+tid]; nb1s[tid] = nb1_[l*64+tid]; }
  __syncthreads();
  int rl = tid >> 2, q = tid & 3;
  int row = blockIdx.x*64 + rl;    // row = b*N + n
  int b = row >> 10, n = row & 1023;
  float hr[64];
  const float4* hp = (const float4*)(h + row*64);
  #pragma unroll
  for (int k4 = 0; k4 < 16; k4++){
    float4 v = hp[k4];
    hr[4*k4] = v.x; hr[4*k4+1] = v.y; hr[4*k4+2] = v.z; hr[4*k4+3] = v.w;
  }
  int tb = (n*16 + b)*64;
  for (int jc = 0; jc < 4; jc++){
    int j0 = q*16 + jc*4;
    float a1x=eb1s[j0], a1y=eb1s[j0+1], a1z=eb1s[j0+2], a1w=eb1s[j0+3];
    float a2x=0.f, a2y=0.f, a2z=0.f, a2w=0.f;
    float a3x=nb1s[j0], a3y=nb1s[j0+1], a3z=nb1s[j0+2], a3w=nb1s[j0+3];
    #pragma unroll
    for (int k = 0; k < 64; k++){
      float hv = hr[k];
      float4 w1 = *(const float4*)(Wa + k*64 + j0);
      float4 w2 = *(const float4*)(Wb + k*64 + j0);
      float4 w3 = *(const float4*)(Wc + k*64 + j0);
      a1x += hv*w1.x; a1y += hv*w1.y; a1z += hv*w1.z; a1w += hv*w1.w;
      a2x += hv*w2.x; a2y += hv*w2.y; a2z += hv*w2.z; a2w += hv*w2.w;
      a3x += hv*w3.x; a3y += hv*w3.y; a3z += hv*w3.z; a3w += hv*w3.w;
    }
    float4 o1 = {a1x,a1y,a1z,a1w};
    float4 o3 = {a3x,a3y,a3z,a3w};
    *(float4*)(A1t + tb + j0) = o1;
    uint2 pk; pk.x = packbf(a2x, a2y); pk.y = packbf(a2z, a2w);
    *(uint2*)(A2bf + tb + j0) = pk;
    *(float4*)(hn + row*64 + j0) = o3;
  }
}

// ---- hot kernel: block = node r; wave = one edge x 16 batches (MFMA) -------
__global__ __launch_bounds__(256, 3) void k_edge(const float* A1t,
      const unsigned short* A2bf, const unsigned short* wfragE,
      const float* eb2, int l, const int* off, const int* ecol, float* aggT){
  __shared__ __align__(16) float A1s[16*68];     // A1[r] rows, pad 68
  __shared__ __align__(16) float aggS[4*16*68];  // per-wave agg partials

  int tid  = threadIdx.x;
  int r    = blockIdx.x;
  int wav  = tid >> 6;
  int lane = tid & 63;
  int m    = lane & 15;        // = batch b (B-operand n-index, D col)
  int quad = lane >> 4;

  // stage A1[r] (fp32) into LDS
  {
    float4 v = *(const float4*)(A1t + r*1024 + tid*4);
    *(float4*)(A1s + (tid>>4)*68 + (tid&15)*4) = v;
  }
  __syncthreads();

  // eW2 A-fragments: 8 frags x 8 bf16, resident in VGPRs
  short8 wf[8];
  #pragma unroll
  for (int f = 0; f < 8; f++)
    wf[f] = *(const short8*)(wfragE + l*4096 + f*512 + lane*8);

  // bias as mfma C-init: dini[jt][reg] = eb2[jt*16 + quad*4 + reg]
  floatx4 dini[4];
  #pragma unroll
  for (int jt = 0; jt < 4; jt++)
    dini[jt] = *(const floatx4*)(eb2 + l*64 + jt*16 + quad*4);

  floatx4 agg[4];
  #pragma unroll
  for (int jt = 0; jt < 4; jt++) agg[jt] = (floatx4){0.f,0.f,0.f,0.f};

  int e0  = off[r];
  int cnt = off[r+1] - e0;

  for (int e = wav; e < cnt; e += 4){
    int c = ecol[e0 + e];
    const unsigned short* a2p = A2bf + (c << 10) + (m << 6);

    // r1 B-fragments: B[n=b][k=quad*8+j8 (+32ks)] = silu(A1 + A2)
    short8 bfr[2];
    #pragma unroll
    for (int ks = 0; ks < 2; ks++){
      uint4 a2r = *(const uint4*)(a2p + ks*32 + quad*8);
      float4 x0 = *(const float4*)(A1s + m*68 + ks*32 + quad*8);
      float4 x1 = *(const float4*)(A1s + m*68 + ks*32 + quad*8 + 4);
      float v0 = siluf(x0.x + bflo(a2r.x));
      float v1 = siluf(x0.y + bfhi(a2r.x));
      float v2 = siluf(x0.z + bflo(a2r.y));
      float v3 = siluf(x0.w + bfhi(a2r.y));
      float v4 = siluf(x1.x + bflo(a2r.z));
      float v5 = siluf(x1.y + bfhi(a2r.z));
      float v6 = siluf(x1.z + bflo(a2r.w));
      float v7 = siluf(x1.w + bfhi(a2r.w));
      union { uint4 u; short8 s; } bu;
      bu.u.x = packbf(v0, v1); bu.u.y = packbf(v2, v3);
      bu.u.z = packbf(v4, v5); bu.u.w = packbf(v6, v7);
      bfr[ks] = bu.s;
    }

    // m-tile = silu(W2^T x r1 + eb2); D: row=j(quad*4+reg), col=b(lane&15)
    #pragma unroll
    for (int jt = 0; jt < 4; jt++){
      floatx4 d = dini[jt];
      d = __builtin_amdgcn_mfma_f32_16x16x32_bf16(wf[jt*2+0], bfr[0], d, 0, 0, 0);
      d = __builtin_amdgcn_mfma_f32_16x16x32_bf16(wf[jt*2+1], bfr[1], d, 0, 0, 0);
      floatx4 a = agg[jt];
      a.x += siluf(d.x); a.y += siluf(d.y);
      a.z += siluf(d.z); a.w += siluf(d.w);
      agg[jt] = a;
    }
  }

  // cross-wave reduce agg -> aggT[r]
  #pragma unroll
  for (int jt = 0; jt < 4; jt++)
    *(floatx4*)(aggS + wav*1088 + m*68 + jt*16 + quad*4) = agg[jt];
  __syncthreads();
  {
    int b = tid >> 4, j0 = (tid & 15)*4;
    float4 s = {0.f,0.f,0.f,0.f};
    #pragma unroll
    for (int w = 0; w < 4; w++){
      float4 v = *(const float4*)(aggS + w*1088 + b*68 + j0);
      s.x += v.x; s.y += v.y; s.z += v.z; s.w += v.w;
    }
    *(float4*)(aggT + r*1024 + b*64 + j0) = s;
  }
}

// ---- node MLP + residual + LayerNorm --------------------------------------
__global__ __launch_bounds__(256) void k_node(float* h, const float* hn, const float* aggT,
      const float* nW1, const float* nW2, const float* nb2_,
      const float* lng_, const float* lnb_, int l){
  __shared__ __align__(16) float W1b[4096];   // nW1[l][64:128]
  __shared__ __align__(16) float W2s[4096];   // nW2[l]
  __shared__ __align__(16) float tl[64*68];
  __shared__ float nb2s[64], lngs[64], lnbs[64];
  int tid = threadIdx.x;
  {
    const float4* n1 = (const float4*)(nW1 + l*8192 + 4096);
    const float4* n2 = (const float4*)(nW2 + l*4096);
    for (int i = tid; i < 1024; i += 256){ ((float4*)W1b)[i] = n1[i]; ((float4*)W2s)[i] = n2[i]; }
  }
  if (tid < 64){
    nb2s[tid] = nb2_[l*64+tid];
    lngs[tid] = lng_[l*64+tid];
    lnbs[tid] = lnb_[l*64+tid];
  }
  __syncthreads();
  int rl = tid >> 2, q = tid & 3;
  int row = blockIdx.x*64 + rl;
  int b = row >> 10, n = row & 1023;
  float ag[64];
  const float4* ap = (const float4*)(aggT + (n*16 + b)*64);
  #pragma unroll
  for (int k4 = 0; k4 < 16; k4++){
    float4 v = ap[k4];
    ag[4*k4] = v.x; ag[4*k4+1] = v.y; ag[4*k4+2] = v.z; ag[4*k4+3] = v.w;
  }
  for (int jc = 0; jc < 4; jc++){
    int j0 = q*16 + jc*4;
    float4 acc = *(const float4*)(hn + row*64 + j0);
    #pragma unroll
    for (int k = 0; k < 64; k++){
      const float4 w = *(const float4*)(W1b + k*64 + j0);
      float a = ag[k];
      acc.x += a*w.x; acc.y += a*w.y; acc.z += a*w.z; acc.w += a*w.w;
    }
    float4 t4 = { siluf(acc.x), siluf(acc.y), siluf(acc.z), siluf(acc.w) };
    *(float4*)(tl + rl*68 + j0) = t4;
  }
  __syncthreads();
  float tr[64];
  #pragma unroll
  for (int k4 = 0; k4 < 16; k4++){
    float4 v = *(const float4*)(tl + rl*68 + k4*4);
    tr[4*k4] = v.x; tr[4*k4+1] = v.y; tr[4*k4+2] = v.z; tr[4*k4+3] = v.w;
  }
  float hv[16];
  #pragma unroll
  for (int jc = 0; jc < 4; jc++){
    int j0 = q*16 + jc*4;
    float ax=nb2s[j0], ay=nb2s[j0+1], az=nb2s[j0+2], aw=nb2s[j0+3];
    #pragma unroll
    for (int k = 0; k < 64; k++){
      const float4 w = *(const float4*)(W2s + k*64 + j0);
      float t = tr[k];
      ax += t*w.x; ay += t*w.y; az += t*w.z; aw += t*w.w;
    }
    const float4 ho = *(const float4*)(h + row*64 + j0);
    hv[4*jc+0] = ho.x + ax; hv[4*jc+1] = ho.y + ay;
    hv[4*jc+2] = ho.z + az; hv[4*jc+3] = ho.w + aw;
  }
  float s1 = 0.f, s2 = 0.f;
  #pragma unroll
  for (int i = 0; i < 16; i++){ s1 += hv[i]; s2 += hv[i]*hv[i]; }
  s1 += __shfl_xor(s1, 1, 64); s1 += __shfl_xor(s1, 2, 64);
  s2 += __shfl_xor(s2, 1, 64); s2 += __shfl_xor(s2, 2, 64);
  float mu  = s1 * (1.0f/64.0f);
  float var = s2 * (1.0f/64.0f) - mu*mu;
  float rs  = rsqrtf(var + 1e-5f);
  #pragma unroll
  for (int jc = 0; jc < 4; jc++){
    int j0 = q*16 + jc*4;
    float4 o;
    o.x = (hv[4*jc+0]-mu)*rs*lngs[j0+0] + lnbs[j0+0];
    o.y = (hv[4*jc+1]-mu)*rs*lngs[j0+1] + lnbs[j0+1];
    o.z = (hv[4*jc+2]-mu)*rs*lngs[j0+2] + lnbs[j0+2];
    o.w = (hv[4*jc+3]-mu)*rs*lngs[j0+3] + lnbs[j0+3];
    *(float4*)(h + row*64 + j0) = o;
  }
}

// ---- output head -----------------------------------------------------------
__global__ __launch_bounds__(256) void k_out(const float* h, const float* oW1,
                                             const float* ob1_, const float* oW2,
                                             const float* ob2_, float* out){
  __shared__ __align__(16) float W1[4096];
  __shared__ __align__(16) float tl[64*68];
  __shared__ float W2[192];
  __shared__ float ob1s[64];
  __shared__ float ob2s[3];
  int tid = threadIdx.x;
  {
    const float4* w1p = (const float4*)oW1;
    for (int i = tid; i < 1024; i += 256) ((float4*)W1)[i] = w1p[i];
  }
  if (tid < 192) W2[tid] = oW2[tid];
  if (tid < 64)  ob1s[tid] = ob1_[tid];
  if (tid < 3)   ob2s[tid] = ob2_[tid];
  __syncthreads();
  int rl = tid >> 2, q = tid & 3;
  int row = blockIdx.x*64 + rl;
  float hr[64];
  const float4* hp = (const float4*)(h + row*64);
  #pragma unroll
  for (int k4 = 0; k4 < 16; k4++){
    float4 v = hp[k4];
    hr[4*k4] = v.x; hr[4*k4+1] = v.y; hr[4*k4+2] = v.z; hr[4*k4+3] = v.w;
  }
  for (int jc = 0; jc < 4; jc++){
    int j0 = q*16 + jc*4;
    float ax=ob1s[j0], ay=ob1s[j0+1], az=ob1s[j0+2], aw=ob1s[j0+3];
    #pragma unroll
    for (int k = 0; k < 64; k++){
      const float4 w = *(const float4*)(W1 + k*64 + j0);
      float hvv = hr[k];
      ax += hvv*w.x; ay += hvv*w.y; az += hvv*w.z; aw += hvv*w.w;
    }
    float4 t4 = { fmaxf(ax,0.f), fmaxf(ay,0.f), fmaxf(az,0.f), fmaxf(aw,0.f) };
    *(float4*)(tl + rl*68 + j0) = t4;
  }
  __syncthreads();
  if (q < 3){
    float acc = ob2s[q];
    #pragma unroll
    for (int k = 0; k < 64; k++) acc += tl[rl*68 + k] * W2[k*3 + q];
    int b = row >> 10, n = row & 1023;
    out[b*3072 + n*3 + q] = acc;
  }
}

} // namespace

extern "C" void kernel_launch(void* const* d_in, const int* in_sizes, int n_in,
                              void* d_out, int out_size, void* d_ws, size_t ws_size,
                              hipStream_t stream){
  const float* z   = (const float*)d_in[0];
  const int*   ei  = (const int*)d_in[1];
  const float* nf  = (const float*)d_in[2];
  const float* Wg  = (const float*)d_in[3];  const float* bg  = (const float*)d_in[4];
  const float* Wn  = (const float*)d_in[5];  const float* bn  = (const float*)d_in[6];
  const float* eW1 = (const float*)d_in[7];  const float* eb1 = (const float*)d_in[8];
  const float* eW2 = (const float*)d_in[9];  const float* eb2 = (const float*)d_in[10];
  const float* nW1 = (const float*)d_in[14]; const float* nb1 = (const float*)d_in[15];
  const float* nW2 = (const float*)d_in[16]; const float* nb2 = (const float*)d_in[17];
  const float* lng = (const float*)d_in[18]; const float* lnb = (const float*)d_in[19];
  const float* oW1 = (const float*)d_in[20]; const float* ob1 = (const float*)d_in[21];
  const float* oW2 = (const float*)d_in[22]; const float* ob2 = (const float*)d_in[23];

  float* W     = (float*)d_ws;
  float* h     = W;                                  // [B*N][64]
  float* A1t   = W + 1048576;                        // [N][B][64] fp32
  float* hn    = W + 2097152;                        // [B*N][64]
  float* aggT  = W + 3145728;                        // [N][B][64]
  unsigned short* A2bf   = (unsigned short*)(W + 4194304);  // [N][B][64] bf16
  unsigned short* wfragE = (unsigned short*)(W + 4718592);  // [L][8][64][8] bf16
  float* g     = W + 4726784;                        // [B][64]
  int*   cntI  = (int*)(W + 4727808);                // [N]
  int*   off   = cntI + 1024;                        // [N+1]
  int*   fill  = off + 1025;                         // [N]
  int*   ecol  = fill + 1024;                        // [E]

  k_g     <<<4,    256, 0, stream>>>(z, Wg, bg, g);
  k_hinit <<<4096, 256, 0, stream>>>(nf, Wn, bn, g, h, cntI);
  k_count <<<128,  256, 0, stream>>>(ei, cntI);
  k_scan  <<<1,   1024, 0, stream>>>(cntI, off, fill);
  k_bucket<<<128,  256, 0, stream>>>(ei, off, fill, ecol);
  k_wfrag <<<4,    256, 0, stream>>>(eW2, wfragE);

  for (int l = 0; l < 4; l++){
    k_nodeA<<<256, 256, 0, stream>>>(h, eW1, eb1, nW1, nb1, l, A1t, A2bf, hn);
    k_edge <<<1024,256, 0, stream>>>(A1t, A2bf, wfragE, eb2, l, off, ecol, aggT);
    k_node <<<256, 256, 0, stream>>>(h, hn, aggT, nW1, nW2, nb2, lng, lnb, l);
  }
  k_out<<<256, 256, 0, stream>>>(h, oW1, ob1, oW2, ob2, (float*)d_out);
}

// Round 4
// 429.769 us; speedup vs baseline: 5.6361x; 1.1000x over previous
//
#include <hip/hip_runtime.h>
#include <hip/hip_bf16.h>

// Decoder (EGNN) on MI355X. pos==0 identity => stage-2/pos/counts dead.
// Per call: memset(cntI), k_count, k_scan (CSR + item list), k_bucket(+wfrag),
// k_pre (g+h+nodeA0), 4x{ k_edge (flat wave-chunks, MFMA, reg-only, partials->P),
// k_post (node MLP+LN + nodeA(l+1), sums P) }, last k_post fuses output head.

namespace {

constexpr int kB = 16, kN = 1024, kH = 64, kE = 32768, kLat = 128;
constexpr int kC = 24;                 // edges per wave-chunk
constexpr int kMaxItems = 2560;        // >= E/kC + N = 2390

typedef __attribute__((ext_vector_type(8))) short short8;   // 8 bf16
typedef __attribute__((ext_vector_type(4))) float floatx4;

__device__ __forceinline__ unsigned short f2bf(float f){   // RNE (tables only)
  union { float f; unsigned int u; } v; v.f = f;
  unsigned int r = v.u + 0x7fffu + ((v.u >> 16) & 1u);
  return (unsigned short)(r >> 16);
}
__device__ __forceinline__ unsigned int packbf(float a, float b){
  return ((unsigned int)f2bf(b) << 16) | (unsigned int)f2bf(a);
}
__device__ __forceinline__ unsigned int pack2f(float a, float b){ // fast half-up
  unsigned int ua = __float_as_uint(a) + 0x8000u;
  unsigned int ub = __float_as_uint(b) + 0x8000u;
  return __builtin_amdgcn_perm(ub, ua, 0x07060302);  // lo16=bf(a), hi16=bf(b)
}
__device__ __forceinline__ float bflo(unsigned int u){
  union { unsigned int u; float f; } v; v.u = u << 16; return v.f;
}
__device__ __forceinline__ float bfhi(unsigned int u){
  union { unsigned int u; float f; } v; v.u = u & 0xffff0000u; return v.f;
}
__device__ __forceinline__ float silu2(float x){   // 2 trans + 3 alu
  float u = __builtin_amdgcn_exp2f(-1.44269504f * x);
  return x * __builtin_amdgcn_rcpf(1.0f + u);
}

// ---- CSR build -------------------------------------------------------------
__global__ void k_count(const int* ei, int* cntI){
  int e = blockIdx.x*256 + threadIdx.x;      // E exactly
  atomicAdd(&cntI[ei[e]], 1);
}

__global__ void k_scan(const int* cntI, int* off, int* ioff, int* fill,
                       int* items, int* nitems){
  __shared__ int s0[1024];
  __shared__ int s1[1024];
  int t = threadIdx.x;
  int c = cntI[t];
  s0[t] = c; __syncthreads();
  int* src = s0; int* dst = s1;
  for (int o = 1; o < 1024; o <<= 1){
    int v = src[t] + ((t >= o) ? src[t-o] : 0);
    dst[t] = v; __syncthreads();
    int* tmp = src; src = dst; dst = tmp;
  }
  int inc = src[t];
  off[t] = inc - c;
  if (t == 1023) off[1024] = inc;
  fill[t] = 0;
  int ic = (c + (kC-1)) / kC;
  __syncthreads();
  s0[t] = ic; __syncthreads();
  src = s0; dst = s1;
  for (int o = 1; o < 1024; o <<= 1){
    int v = src[t] + ((t >= o) ? src[t-o] : 0);
    dst[t] = v; __syncthreads();
    int* tmp = src; src = dst; dst = tmp;
  }
  int inc2 = src[t];
  int ib = inc2 - ic;
  ioff[t] = ib;
  if (t == 1023){ ioff[1024] = inc2; *nitems = inc2; }
  for (int s = 0; s < ic; s++) items[ib + s] = (t << 12) | s;
}

// ---- bucket + (blocks 0-3) eW2 -> A-fragment table -------------------------
__global__ void k_bucket(const int* ei, const int* off, int* fill, int* ecol,
                         const float* eW2, unsigned short* wfragE){
  int e = blockIdx.x*256 + threadIdx.x;
  int r = ei[e];
  int s = atomicAdd(&fill[r], 1);
  ecol[off[r] + s] = ei[kE + e];
  if (blockIdx.x < 4){
    int l = blockIdx.x;
    for (int i = threadIdx.x; i < 4096; i += 256){
      int f = i >> 9, lane = (i >> 3) & 63, j8 = i & 7;
      int jt = f >> 1, ks = f & 1;
      int k = ks*32 + (lane >> 4)*8 + j8;
      int j = jt*16 + (lane & 15);
      wfragE[l*4096 + i] = f2bf(eW2[l*4096 + k*64 + j]);
    }
  }
}

// ---- k_pre: g, h-init, nodeA(l=0) ------------------------------------------
__global__ __launch_bounds__(256, 1) void k_pre(const float* z, const float* Wg,
      const float* bg, const float* nf, const float* Wn, const float* bn,
      const float* eW1, const float* eb1, float* h, float* A1t,
      unsigned short* A2bf){
  __shared__ __align__(16) float WA[4096];
  __shared__ __align__(16) float WB[4096];
  __shared__ __align__(16) float HS[64*68];
  __shared__ float gP[4][64];
  __shared__ float gS[64], eb1s[64];
  int tid = threadIdx.x;
  int bb = blockIdx.x >> 4;
  int n0 = (blockIdx.x & 15) * 64;
  {
    const float4* e1a = (const float4*)(eW1);
    const float4* e1b = (const float4*)(eW1 + 4096);
    for (int i = tid; i < 1024; i += 256){ ((float4*)WA)[i] = e1a[i]; ((float4*)WB)[i] = e1b[i]; }
  }
  if (tid < 64) eb1s[tid] = eb1[tid];
  {
    int j = tid & 63, p = tid >> 6;
    float acc = 0.f;
    for (int k = p*32; k < p*32+32; k++) acc += z[bb*kLat + k] * Wg[k*64 + j];
    gP[p][j] = acc;
  }
  __syncthreads();
  if (tid < 64) gS[tid] = bg[tid] + gP[0][tid] + gP[1][tid] + gP[2][tid] + gP[3][tid];
  __syncthreads();
  int rl = tid >> 2, q = tid & 3;
  int n = n0 + rl;
  int row = bb*1024 + n;
  float f0 = nf[n*3], f1 = nf[n*3+1], f2 = nf[n*3+2];
  #pragma unroll
  for (int jc = 0; jc < 4; jc++){
    float4 v;
    int j = q*16 + jc*4;
    v.x = f0*Wn[j+0] + f1*Wn[64+j+0] + f2*Wn[128+j+0] + bn[j+0] + gS[j+0];
    v.y = f0*Wn[j+1] + f1*Wn[64+j+1] + f2*Wn[128+j+1] + bn[j+1] + gS[j+1];
    v.z = f0*Wn[j+2] + f1*Wn[64+j+2] + f2*Wn[128+j+2] + bn[j+2] + gS[j+2];
    v.w = f0*Wn[j+3] + f1*Wn[64+j+3] + f2*Wn[128+j+3] + bn[j+3] + gS[j+3];
    *(float4*)(h + row*64 + j) = v;
    *(float4*)(HS + rl*68 + j) = v;
  }
  __syncthreads();
  float hr[64];
  #pragma unroll
  for (int k4 = 0; k4 < 16; k4++){
    float4 v = *(const float4*)(HS + rl*68 + k4*4);
    hr[4*k4] = v.x; hr[4*k4+1] = v.y; hr[4*k4+2] = v.z; hr[4*k4+3] = v.w;
  }
  int tb = (n*16 + bb)*64;
  for (int jc = 0; jc < 4; jc++){
    int j0 = q*16 + jc*4;
    float a1x=eb1s[j0], a1y=eb1s[j0+1], a1z=eb1s[j0+2], a1w=eb1s[j0+3];
    float a2x=0.f, a2y=0.f, a2z=0.f, a2w=0.f;
    #pragma unroll
    for (int k = 0; k < 64; k++){
      float hv = hr[k];
      float4 w1 = *(const float4*)(WA + k*64 + j0);
      float4 w2 = *(const float4*)(WB + k*64 + j0);
      a1x += hv*w1.x; a1y += hv*w1.y; a1z += hv*w1.z; a1w += hv*w1.w;
      a2x += hv*w2.x; a2y += hv*w2.y; a2z += hv*w2.z; a2w += hv*w2.w;
    }
    float4 o1 = {a1x,a1y,a1z,a1w};
    *(float4*)(A1t + tb + j0) = o1;
    uint2 pk; pk.x = packbf(a2x, a2y); pk.y = packbf(a2z, a2w);
    *(uint2*)(A2bf + tb + j0) = pk;
  }
}

// ---- hot kernel: wave = one (node, <=24-edge chunk); registers only --------
__global__ __launch_bounds__(256, 3) void k_edge(const float* A1t,
      const unsigned short* A2bf, const unsigned short* wfragE,
      const float* eb2, int l, const int* off, const int* ecol,
      const int* items, const int* nitems, float* P){
  int w = blockIdx.x*4 + (threadIdx.x >> 6);
  if (w >= *nitems) return;
  int lane = threadIdx.x & 63;
  int m = lane & 15, quad = lane >> 4;
  int it = items[w];
  int r = it >> 12, s = it & 4095;
  int e0 = off[r] + s*kC;
  int e1 = min(off[r+1], e0 + kC);

  short8 wf[8];
  #pragma unroll
  for (int f = 0; f < 8; f++)
    wf[f] = *(const short8*)(wfragE + l*4096 + f*512 + lane*8);

  float4 a1[4];   // a1[ks*2+half]
  #pragma unroll
  for (int ks = 0; ks < 2; ks++){
    a1[ks*2+0] = *(const float4*)(A1t + (r<<10) + (m<<6) + ks*32 + quad*8);
    a1[ks*2+1] = *(const float4*)(A1t + (r<<10) + (m<<6) + ks*32 + quad*8 + 4);
  }
  floatx4 dini[4];
  #pragma unroll
  for (int jt = 0; jt < 4; jt++)
    dini[jt] = *(const floatx4*)(eb2 + l*64 + jt*16 + quad*4);
  floatx4 agg[4];
  #pragma unroll
  for (int jt = 0; jt < 4; jt++) agg[jt] = (floatx4){0.f,0.f,0.f,0.f};

  // depth-1 pipelined A2 gather
  int c0 = ecol[e0];
  uint4 p0 = *(const uint4*)(A2bf + ((c0<<4)+m)*64 + quad*8);
  uint4 p1 = *(const uint4*)(A2bf + ((c0<<4)+m)*64 + 32 + quad*8);

  for (int e = e0; e < e1; e++){
    uint4 c_0 = p0, c_1 = p1;
    if (e + 1 < e1){
      int cn = ecol[e+1];
      p0 = *(const uint4*)(A2bf + ((cn<<4)+m)*64 + quad*8);
      p1 = *(const uint4*)(A2bf + ((cn<<4)+m)*64 + 32 + quad*8);
    }
    short8 bfr[2];
    #pragma unroll
    for (int ks = 0; ks < 2; ks++){
      uint4 a2r = (ks == 0) ? c_0 : c_1;
      float4 x0 = a1[ks*2+0];
      float4 x1 = a1[ks*2+1];
      float v0 = silu2(x0.x + bflo(a2r.x));
      float v1 = silu2(x0.y + bfhi(a2r.x));
      float v2 = silu2(x0.z + bflo(a2r.y));
      float v3 = silu2(x0.w + bfhi(a2r.y));
      float v4 = silu2(x1.x + bflo(a2r.z));
      float v5 = silu2(x1.y + bfhi(a2r.z));
      float v6 = silu2(x1.z + bflo(a2r.w));
      float v7 = silu2(x1.w + bfhi(a2r.w));
      union { uint4 u; short8 s; } bu;
      bu.u.x = pack2f(v0, v1); bu.u.y = pack2f(v2, v3);
      bu.u.z = pack2f(v4, v5); bu.u.w = pack2f(v6, v7);
      bfr[ks] = bu.s;
    }
    #pragma unroll
    for (int jt = 0; jt < 4; jt++){
      floatx4 d = dini[jt];
      d = __builtin_amdgcn_mfma_f32_16x16x32_bf16(wf[jt*2+0], bfr[0], d, 0, 0, 0);
      d = __builtin_amdgcn_mfma_f32_16x16x32_bf16(wf[jt*2+1], bfr[1], d, 0, 0, 0);
      floatx4 a = agg[jt];
      a.x += silu2(d.x); a.y += silu2(d.y);
      a.z += silu2(d.z); a.w += silu2(d.w);
      agg[jt] = a;
    }
  }
  #pragma unroll
  for (int jt = 0; jt < 4; jt++)
    *(floatx4*)(P + w*1024 + m*64 + jt*16 + quad*4) = agg[jt];
}

// ---- k_post: node MLP + LN (+ nodeA(l+1) or output head) -------------------
template <bool LAST>
__global__ __launch_bounds__(256, 1) void k_post(int l, float* h, const float* P,
      const int* ioff, const float* nW1, const float* nb1_, const float* nW2,
      const float* nb2_, const float* lng_, const float* lnb_,
      const float* eW1, const float* eb1_, float* A1t, unsigned short* A2bf,
      const float* oW1, const float* ob1_, const float* oW2, const float* ob2_,
      float* out){
  __shared__ __align__(16) float WA[4096];
  __shared__ __align__(16) float WB[4096];
  __shared__ __align__(16) float WC[4096];
  __shared__ __align__(16) float TL[64*68];
  __shared__ __align__(16) float HS[64*68];
  __shared__ float b1s[64], b2s[64], lgs[64], lbs[64];
  __shared__ float W2o[192];
  __shared__ float ob2s[4];
  int tid = threadIdx.x;
  int bb = blockIdx.x >> 4;
  int n0 = (blockIdx.x & 15) * 64;
  {
    const float4* p1 = (const float4*)(nW1 + l*8192);
    const float4* p2 = (const float4*)(nW1 + l*8192 + 4096);
    const float4* p3 = (const float4*)(nW2 + l*4096);
    for (int i = tid; i < 1024; i += 256){
      ((float4*)WA)[i] = p1[i]; ((float4*)WB)[i] = p2[i]; ((float4*)WC)[i] = p3[i];
    }
  }
  if (tid < 64){
    b1s[tid] = nb1_[l*64+tid]; b2s[tid] = nb2_[l*64+tid];
    lgs[tid] = lng_[l*64+tid]; lbs[tid] = lnb_[l*64+tid];
  }
  __syncthreads();
  int rl = tid >> 2, q = tid & 3;
  int n = n0 + rl;
  int row = bb*1024 + n;
  float hr[64];
  {
    const float4* hp = (const float4*)(h + row*64);
    #pragma unroll
    for (int k4 = 0; k4 < 16; k4++){
      float4 v = hp[k4];
      hr[4*k4] = v.x; hr[4*k4+1] = v.y; hr[4*k4+2] = v.z; hr[4*k4+3] = v.w;
    }
  }
  float ag[64];
  #pragma unroll
  for (int k = 0; k < 64; k++) ag[k] = 0.f;
  {
    int i0 = ioff[n], i1 = ioff[n+1];
    for (int i = i0; i < i1; i++){
      const float4* pp = (const float4*)(P + i*1024 + bb*64);
      #pragma unroll
      for (int k4 = 0; k4 < 16; k4++){
        float4 v = pp[k4];
        ag[4*k4] += v.x; ag[4*k4+1] += v.y; ag[4*k4+2] += v.z; ag[4*k4+3] += v.w;
      }
    }
  }
  // t = silu(hr@nW1lo + ag@nW1hi + nb1)
  for (int jc = 0; jc < 4; jc++){
    int j0 = q*16 + jc*4;
    float ax=b1s[j0], ay=b1s[j0+1], az=b1s[j0+2], aw=b1s[j0+3];
    #pragma unroll
    for (int k = 0; k < 64; k++){
      float hv = hr[k], av = ag[k];
      float4 w1 = *(const float4*)(WA + k*64 + j0);
      float4 w2 = *(const float4*)(WB + k*64 + j0);
      ax += hv*w1.x + av*w2.x; ay += hv*w1.y + av*w2.y;
      az += hv*w1.z + av*w2.z; aw += hv*w1.w + av*w2.w;
    }
    float4 t4 = { silu2(ax), silu2(ay), silu2(az), silu2(aw) };
    *(float4*)(TL + rl*68 + j0) = t4;
  }
  __syncthreads();
  float tr[64];
  #pragma unroll
  for (int k4 = 0; k4 < 16; k4++){
    float4 v = *(const float4*)(TL + rl*68 + k4*4);
    tr[4*k4] = v.x; tr[4*k4+1] = v.y; tr[4*k4+2] = v.z; tr[4*k4+3] = v.w;
  }
  float hv16[16];
  #pragma unroll
  for (int jc = 0; jc < 4; jc++){
    int j0 = q*16 + jc*4;
    float ax=b2s[j0], ay=b2s[j0+1], az=b2s[j0+2], aw=b2s[j0+3];
    #pragma unroll
    for (int k = 0; k < 64; k++){
      float t = tr[k];
      float4 w = *(const float4*)(WC + k*64 + j0);
      ax += t*w.x; ay += t*w.y; az += t*w.z; aw += t*w.w;
    }
    hv16[4*jc+0] = hr[j0+0] + ax; hv16[4*jc+1] = hr[j0+1] + ay;
    hv16[4*jc+2] = hr[j0+2] + az; hv16[4*jc+3] = hr[j0+3] + aw;
  }
  float s1 = 0.f, s2 = 0.f;
  #pragma unroll
  for (int i = 0; i < 16; i++){ s1 += hv16[i]; s2 += hv16[i]*hv16[i]; }
  s1 += __shfl_xor(s1, 1, 64); s1 += __shfl_xor(s1, 2, 64);
  s2 += __shfl_xor(s2, 1, 64); s2 += __shfl_xor(s2, 2, 64);
  float mu  = s1 * (1.0f/64.0f);
  float var = s2 * (1.0f/64.0f) - mu*mu;
  float rs  = rsqrtf(var + 1e-5f);
  #pragma unroll
  for (int jc = 0; jc < 4; jc++){
    int j0 = q*16 + jc*4;
    float4 o;
    o.x = (hv16[4*jc+0]-mu)*rs*lgs[j0+0] + lbs[j0+0];
    o.y = (hv16[4*jc+1]-mu)*rs*lgs[j0+1] + lbs[j0+1];
    o.z = (hv16[4*jc+2]-mu)*rs*lgs[j0+2] + lbs[j0+2];
    o.w = (hv16[4*jc+3]-mu)*rs*lgs[j0+3] + lbs[j0+3];
    if (!LAST) *(float4*)(h + row*64 + j0) = o;
    *(float4*)(HS + rl*68 + j0) = o;
  }
  __syncthreads();

  if (!LAST){
    // nodeA(l+1)
    {
      const float4* e1a = (const float4*)(eW1 + (l+1)*8256);
      const float4* e1b = (const float4*)(eW1 + (l+1)*8256 + 4096);
      for (int i = tid; i < 1024; i += 256){ ((float4*)WA)[i] = e1a[i]; ((float4*)WB)[i] = e1b[i]; }
    }
    if (tid < 64) b1s[tid] = eb1_[(l+1)*64 + tid];
    __syncthreads();
    float h2[64];
    #pragma unroll
    for (int k4 = 0; k4 < 16; k4++){
      float4 v = *(const float4*)(HS + rl*68 + k4*4);
      h2[4*k4] = v.x; h2[4*k4+1] = v.y; h2[4*k4+2] = v.z; h2[4*k4+3] = v.w;
    }
    int tb = (n*16 + bb)*64;
    for (int jc = 0; jc < 4; jc++){
      int j0 = q*16 + jc*4;
      float a1x=b1s[j0], a1y=b1s[j0+1], a1z=b1s[j0+2], a1w=b1s[j0+3];
      float a2x=0.f, a2y=0.f, a2z=0.f, a2w=0.f;
      #pragma unroll
      for (int k = 0; k < 64; k++){
        float hvv = h2[k];
        float4 w1 = *(const float4*)(WA + k*64 + j0);
        float4 w2 = *(const float4*)(WB + k*64 + j0);
        a1x += hvv*w1.x; a1y += hvv*w1.y; a1z += hvv*w1.z; a1w += hvv*w1.w;
        a2x += hvv*w2.x; a2y += hvv*w2.y; a2z += hvv*w2.z; a2w += hvv*w2.w;
      }
      float4 o1 = {a1x,a1y,a1z,a1w};
      *(float4*)(A1t + tb + j0) = o1;
      uint2 pk; pk.x = packbf(a2x, a2y); pk.y = packbf(a2z, a2w);
      *(uint2*)(A2bf + tb + j0) = pk;
    }
  } else {
    // output head
    {
      const float4* w1p = (const float4*)oW1;
      for (int i = tid; i < 1024; i += 256) ((float4*)WA)[i] = w1p[i];
    }
    if (tid < 192) W2o[tid] = oW2[tid];
    if (tid < 64)  b1s[tid] = ob1_[tid];
    if (tid < 3)   ob2s[tid] = ob2_[tid];
    __syncthreads();
    float h2[64];
    #pragma unroll
    for (int k4 = 0; k4 < 16; k4++){
      float4 v = *(const float4*)(HS + rl*68 + k4*4);
      h2[4*k4] = v.x; h2[4*k4+1] = v.y; h2[4*k4+2] = v.z; h2[4*k4+3] = v.w;
    }
    for (int jc = 0; jc < 4; jc++){
      int j0 = q*16 + jc*4;
      float ax=b1s[j0], ay=b1s[j0+1], az=b1s[j0+2], aw=b1s[j0+3];
      #pragma unroll
      for (int k = 0; k < 64; k++){
        float hvv = h2[k];
        float4 w = *(const float4*)(WA + k*64 + j0);
        ax += hvv*w.x; ay += hvv*w.y; az += hvv*w.z; aw += hvv*w.w;
      }
      float4 t4 = { fmaxf(ax,0.f), fmaxf(ay,0.f), fmaxf(az,0.f), fmaxf(aw,0.f) };
      *(float4*)(TL + rl*68 + j0) = t4;
    }
    __syncthreads();
    if (q < 3){
      float acc = ob2s[q];
      #pragma unroll
      for (int k = 0; k < 64; k++) acc += TL[rl*68 + k] * W2o[k*3 + q];
      out[bb*3072 + n*3 + q] = acc;
    }
  }
}

} // namespace

extern "C" void kernel_launch(void* const* d_in, const int* in_sizes, int n_in,
                              void* d_out, int out_size, void* d_ws, size_t ws_size,
                              hipStream_t stream){
  const float* z   = (const float*)d_in[0];
  const int*   ei  = (const int*)d_in[1];
  const float* nf  = (const float*)d_in[2];
  const float* Wg  = (const float*)d_in[3];  const float* bg  = (const float*)d_in[4];
  const float* Wn  = (const float*)d_in[5];  const float* bn  = (const float*)d_in[6];
  const float* eW1 = (const float*)d_in[7];  const float* eb1 = (const float*)d_in[8];
  const float* eW2 = (const float*)d_in[9];  const float* eb2 = (const float*)d_in[10];
  const float* nW1 = (const float*)d_in[14]; const float* nb1 = (const float*)d_in[15];
  const float* nW2 = (const float*)d_in[16]; const float* nb2 = (const float*)d_in[17];
  const float* lng = (const float*)d_in[18]; const float* lnb = (const float*)d_in[19];
  const float* oW1 = (const float*)d_in[20]; const float* ob1 = (const float*)d_in[21];
  const float* oW2 = (const float*)d_in[22]; const float* ob2 = (const float*)d_in[23];

  float* W      = (float*)d_ws;
  float* h      = W;                                   // 1,048,576 f
  float* A1t    = W + 1048576;                         // 1,048,576 f
  unsigned short* A2bf   = (unsigned short*)(W + 2097152); // 1,048,576 bf16
  unsigned short* wfragE = (unsigned short*)(W + 2621440); // 16,384 bf16
  float* P      = W + 2629632;                         // 2560*1024 f
  int*   cntI   = (int*)(W + 5251072);                 // 1024
  int*   off    = cntI + 1024;                         // 1025
  int*   ioff   = off + 1025;                          // 1025
  int*   fill   = ioff + 1025;                         // 1024
  int*   items  = fill + 1024;                         // 2560
  int*   nitems = items + 2560;                        // 1
  int*   ecol   = nitems + 1;                          // 32768

  hipMemsetAsync(cntI, 0, 1024*sizeof(int), stream);
  k_count <<<128, 256, 0, stream>>>(ei, cntI);
  k_scan  <<<1,  1024, 0, stream>>>(cntI, off, ioff, fill, items, nitems);
  k_bucket<<<128, 256, 0, stream>>>(ei, off, fill, ecol, eW2, wfragE);
  k_pre   <<<256, 256, 0, stream>>>(z, Wg, bg, nf, Wn, bn, eW1, eb1, h, A1t, A2bf);

  for (int l = 0; l < 4; l++){
    k_edge<<<640, 256, 0, stream>>>(A1t, A2bf, wfragE, eb2, l, off, ecol,
                                    items, nitems, P);
    if (l < 3)
      k_post<false><<<256, 256, 0, stream>>>(l, h, P, ioff, nW1, nb1, nW2, nb2,
            lng, lnb, eW1, eb1, A1t, A2bf, oW1, ob1, oW2, ob2, (float*)d_out);
    else
      k_post<true> <<<256, 256, 0, stream>>>(l, h, P, ioff, nW1, nb1, nW2, nb2,
            lng, lnb, eW1, eb1, A1t, A2bf, oW1, ob1, oW2, ob2, (float*)d_out);
  }
}

// Round 5
// 366.883 us; speedup vs baseline: 6.6022x; 1.1714x over previous
//
#include <hip/hip_runtime.h>
#include <hip/hip_bf16.h>

// Decoder (EGNN) on MI355X. pos==0 identity => stage-2/pos/counts dead.
// Pipeline: memset(cntI), k_count, k_scan (CSR + wave-chunk items),
// k_bucket (+wfrag blocks 0-3, +g GEMM blocks 4-7), k_pre (h init + nodeA0),
// 4x{ k_edge (wave=24-edge chunk, MFMA, reg-only), k_post (node MLP+LN +
// nodeA(l+1) | output head) }.
// k_post/k_pre: 1024 blocks x 16 rows, 16 thr/row; weights staged 2x16KB at a
// time with phase re-staging -> ~46KB LDS -> 3 blocks/CU (round-4 fusion was
// 147KB -> 1 block/CU -> 8% occupancy, the measured bottleneck).

namespace {

constexpr int kB = 16, kN = 1024, kH = 64, kE = 32768, kLat = 128;
constexpr int kC = 24;                 // edges per wave-chunk
constexpr int kMaxItems = 2560;        // >= sum ceil(deg/kC) (~2390)

typedef __attribute__((ext_vector_type(8))) short short8;   // 8 bf16
typedef __attribute__((ext_vector_type(4))) float floatx4;

__device__ __forceinline__ unsigned short f2bf(float f){   // RNE
  union { float f; unsigned int u; } v; v.f = f;
  unsigned int r = v.u + 0x7fffu + ((v.u >> 16) & 1u);
  return (unsigned short)(r >> 16);
}
__device__ __forceinline__ unsigned int packbf(float a, float b){
  return ((unsigned int)f2bf(b) << 16) | (unsigned int)f2bf(a);
}
__device__ __forceinline__ unsigned int pack2f(float a, float b){ // fast half-up
  unsigned int ua = __float_as_uint(a) + 0x8000u;
  unsigned int ub = __float_as_uint(b) + 0x8000u;
  return __builtin_amdgcn_perm(ub, ua, 0x07060302);
}
__device__ __forceinline__ float bflo(unsigned int u){
  union { unsigned int u; float f; } v; v.u = u << 16; return v.f;
}
__device__ __forceinline__ float bfhi(unsigned int u){
  union { unsigned int u; float f; } v; v.u = u & 0xffff0000u; return v.f;
}
__device__ __forceinline__ float silu2(float x){   // 2 trans + 3 alu
  float u = __builtin_amdgcn_exp2f(-1.44269504f * x);
  return x * __builtin_amdgcn_rcpf(1.0f + u);
}

// ---- CSR build -------------------------------------------------------------
__global__ void k_count(const int* ei, int* cntI){
  int e = blockIdx.x*256 + threadIdx.x;
  atomicAdd(&cntI[ei[e]], 1);
}

__global__ void k_scan(const int* cntI, int* off, int* ioff, int* fill,
                       int* items, int* nitems){
  __shared__ int s0[1024];
  __shared__ int s1[1024];
  int t = threadIdx.x;
  int c = cntI[t];
  s0[t] = c; __syncthreads();
  int* src = s0; int* dst = s1;
  for (int o = 1; o < 1024; o <<= 1){
    int v = src[t] + ((t >= o) ? src[t-o] : 0);
    dst[t] = v; __syncthreads();
    int* tmp = src; src = dst; dst = tmp;
  }
  int inc = src[t];
  off[t] = inc - c;
  if (t == 1023) off[1024] = inc;
  fill[t] = 0;
  int ic = (c + (kC-1)) / kC;
  __syncthreads();
  s0[t] = ic; __syncthreads();
  src = s0; dst = s1;
  for (int o = 1; o < 1024; o <<= 1){
    int v = src[t] + ((t >= o) ? src[t-o] : 0);
    dst[t] = v; __syncthreads();
    int* tmp = src; src = dst; dst = tmp;
  }
  int inc2 = src[t];
  int ib = inc2 - ic;
  ioff[t] = ib;
  if (t == 1023){ ioff[1024] = inc2; *nitems = inc2; }
  for (int s = 0; s < ic; s++) items[ib + s] = (t << 12) | s;
}

// ---- bucket + wfrag (blocks 0-3) + g GEMM (blocks 4-7) ---------------------
__global__ void k_bucket(const int* ei, const int* off, int* fill, int* ecol,
                         const float* eW2, unsigned short* wfragE,
                         const float* z, const float* Wg, const float* bg,
                         float* g){
  int e = blockIdx.x*256 + threadIdx.x;
  int r = ei[e];
  int s = atomicAdd(&fill[r], 1);
  ecol[off[r] + s] = ei[kE + e];
  if (blockIdx.x < 4){
    int l = blockIdx.x;
    for (int i = threadIdx.x; i < 4096; i += 256){
      int f = i >> 9, lane = (i >> 3) & 63, j8 = i & 7;
      int jt = f >> 1, ks = f & 1;
      int k = ks*32 + (lane >> 4)*8 + j8;
      int j = jt*16 + (lane & 15);
      wfragE[l*4096 + i] = f2bf(eW2[l*4096 + k*64 + j]);
    }
  } else if (blockIdx.x < 8){
    int b = (blockIdx.x - 4)*4 + (threadIdx.x >> 6);
    int j = threadIdx.x & 63;
    float acc = bg[j];
    for (int k = 0; k < kLat; k++) acc += z[b*kLat + k] * Wg[k*64 + j];
    g[b*64 + j] = acc;
  }
}

// ---- k_pre: h init + nodeA(0). 1024 blocks x 16 rows x 16 thr/row ----------
__global__ __launch_bounds__(256, 3) void k_pre(const float* nf, const float* Wn,
      const float* bn, const float* g, const float* eW1, const float* eb1,
      float* h, float* A1t, unsigned short* A2bf){
  __shared__ __align__(16) float W0[4096];
  __shared__ __align__(16) float W1[4096];
  __shared__ __align__(16) float HR[16*68];
  __shared__ float b1s[64];
  int tid = threadIdx.x;
  int bb = blockIdx.x >> 6;
  int n0 = (blockIdx.x & 63) * 16;
  {
    const float4* e1a = (const float4*)(eW1);
    const float4* e1b = (const float4*)(eW1 + 4096);
    for (int i = tid; i < 1024; i += 256){ ((float4*)W0)[i] = e1a[i]; ((float4*)W1)[i] = e1b[i]; }
  }
  if (tid < 64) b1s[tid] = eb1[tid];
  int rl = tid >> 4, c = tid & 15, j0 = c*4;
  int n = n0 + rl;
  int row = bb*1024 + n;
  float f0 = nf[n*3], f1 = nf[n*3+1], f2 = nf[n*3+2];
  float4 hv;
  hv.x = f0*Wn[j0+0] + f1*Wn[64+j0+0] + f2*Wn[128+j0+0] + bn[j0+0] + g[bb*64+j0+0];
  hv.y = f0*Wn[j0+1] + f1*Wn[64+j0+1] + f2*Wn[128+j0+1] + bn[j0+1] + g[bb*64+j0+1];
  hv.z = f0*Wn[j0+2] + f1*Wn[64+j0+2] + f2*Wn[128+j0+2] + bn[j0+2] + g[bb*64+j0+2];
  hv.w = f0*Wn[j0+3] + f1*Wn[64+j0+3] + f2*Wn[128+j0+3] + bn[j0+3] + g[bb*64+j0+3];
  *(float4*)(h + row*64 + j0) = hv;
  *(float4*)(HR + rl*68 + j0) = hv;
  __syncthreads();
  float4 a1 = { b1s[j0], b1s[j0+1], b1s[j0+2], b1s[j0+3] };
  float4 a2 = { 0.f, 0.f, 0.f, 0.f };
  #pragma unroll 8
  for (int k = 0; k < 64; k++){
    float hk = HR[rl*68 + k];
    float4 w1 = *(const float4*)(W0 + k*64 + j0);
    float4 w2 = *(const float4*)(W1 + k*64 + j0);
    a1.x += hk*w1.x; a1.y += hk*w1.y; a1.z += hk*w1.z; a1.w += hk*w1.w;
    a2.x += hk*w2.x; a2.y += hk*w2.y; a2.z += hk*w2.z; a2.w += hk*w2.w;
  }
  int tb = (n*16 + bb)*64;
  *(float4*)(A1t + tb + j0) = a1;
  uint2 pk; pk.x = packbf(a2.x, a2.y); pk.y = packbf(a2.z, a2.w);
  *(uint2*)(A2bf + tb + j0) = pk;
}

// ---- hot kernel: wave = one (node, <=24-edge chunk); registers only --------
__global__ __launch_bounds__(256, 3) void k_edge(const float* A1t,
      const unsigned short* A2bf, const unsigned short* wfragE,
      const float* eb2, int l, const int* off, const int* ecol,
      const int* items, const int* nitems, float* P){
  int w = blockIdx.x*4 + (threadIdx.x >> 6);
  if (w >= *nitems) return;
  int lane = threadIdx.x & 63;
  int m = lane & 15, quad = lane >> 4;
  int it = items[w];
  int r = it >> 12, s = it & 4095;
  int e0 = off[r] + s*kC;
  int e1 = min(off[r+1], e0 + kC);

  short8 wf[8];
  #pragma unroll
  for (int f = 0; f < 8; f++)
    wf[f] = *(const short8*)(wfragE + l*4096 + f*512 + lane*8);

  float4 a1[4];
  #pragma unroll
  for (int ks = 0; ks < 2; ks++){
    a1[ks*2+0] = *(const float4*)(A1t + (r<<10) + (m<<6) + ks*32 + quad*8);
    a1[ks*2+1] = *(const float4*)(A1t + (r<<10) + (m<<6) + ks*32 + quad*8 + 4);
  }
  floatx4 dini[4];
  #pragma unroll
  for (int jt = 0; jt < 4; jt++)
    dini[jt] = *(const floatx4*)(eb2 + l*64 + jt*16 + quad*4);
  floatx4 agg[4];
  #pragma unroll
  for (int jt = 0; jt < 4; jt++) agg[jt] = (floatx4){0.f,0.f,0.f,0.f};

  int c0 = ecol[e0];
  uint4 p0 = *(const uint4*)(A2bf + ((c0<<4)+m)*64 + quad*8);
  uint4 p1 = *(const uint4*)(A2bf + ((c0<<4)+m)*64 + 32 + quad*8);

  for (int e = e0; e < e1; e++){
    uint4 c_0 = p0, c_1 = p1;
    if (e + 1 < e1){
      int cn = ecol[e+1];
      p0 = *(const uint4*)(A2bf + ((cn<<4)+m)*64 + quad*8);
      p1 = *(const uint4*)(A2bf + ((cn<<4)+m)*64 + 32 + quad*8);
    }
    short8 bfr[2];
    #pragma unroll
    for (int ks = 0; ks < 2; ks++){
      uint4 a2r = (ks == 0) ? c_0 : c_1;
      float4 x0 = a1[ks*2+0];
      float4 x1 = a1[ks*2+1];
      float v0 = silu2(x0.x + bflo(a2r.x));
      float v1 = silu2(x0.y + bfhi(a2r.x));
      float v2 = silu2(x0.z + bflo(a2r.y));
      float v3 = silu2(x0.w + bfhi(a2r.y));
      float v4 = silu2(x1.x + bflo(a2r.z));
      float v5 = silu2(x1.y + bfhi(a2r.z));
      float v6 = silu2(x1.z + bflo(a2r.w));
      float v7 = silu2(x1.w + bfhi(a2r.w));
      union { uint4 u; short8 s; } bu;
      bu.u.x = pack2f(v0, v1); bu.u.y = pack2f(v2, v3);
      bu.u.z = pack2f(v4, v5); bu.u.w = pack2f(v6, v7);
      bfr[ks] = bu.s;
    }
    #pragma unroll
    for (int jt = 0; jt < 4; jt++){
      floatx4 d = dini[jt];
      d = __builtin_amdgcn_mfma_f32_16x16x32_bf16(wf[jt*2+0], bfr[0], d, 0, 0, 0);
      d = __builtin_amdgcn_mfma_f32_16x16x32_bf16(wf[jt*2+1], bfr[1], d, 0, 0, 0);
      floatx4 a = agg[jt];
      a.x += silu2(d.x); a.y += silu2(d.y);
      a.z += silu2(d.z); a.w += silu2(d.w);
      agg[jt] = a;
    }
  }
  #pragma unroll
  for (int jt = 0; jt < 4; jt++)
    *(floatx4*)(P + w*1024 + m*64 + jt*16 + quad*4) = agg[jt];
}

// ---- k_post: node MLP + LN (+ nodeA(l+1) | output head) --------------------
// 1024 blocks x 16 rows x 16 thr/row; phased weight staging (2x16KB live).
template <bool LAST>
__global__ __launch_bounds__(256, 3) void k_post(int l, float* h, const float* P,
      const int* ioff, const float* nW1, const float* nb1_, const float* nW2,
      const float* nb2_, const float* lng_, const float* lnb_,
      const float* eW1, const float* eb1_, float* A1t, unsigned short* A2bf,
      const float* oW1, const float* ob1_, const float* oW2, const float* ob2_,
      float* out){
  __shared__ __align__(16) float W0[4096];
  __shared__ __align__(16) float W1[4096];
  __shared__ __align__(16) float HR[16*68];
  __shared__ __align__(16) float AG[16*68];
  __shared__ __align__(16) float TL[16*68];
  __shared__ float b1s[64], b2s[64], lgs[64], lbs[64];
  __shared__ float W2o[192];
  __shared__ float ob2s[4];
  int tid = threadIdx.x;
  int bb = blockIdx.x >> 6;
  int n0 = (blockIdx.x & 63) * 16;
  int rl = tid >> 4, c = tid & 15, j0 = c*4;
  int n = n0 + rl;
  int row = bb*1024 + n;

  { // stage nW1 lo|hi
    const float4* p1 = (const float4*)(nW1 + l*8192);
    const float4* p2 = (const float4*)(nW1 + l*8192 + 4096);
    for (int i = tid; i < 1024; i += 256){ ((float4*)W0)[i] = p1[i]; ((float4*)W1)[i] = p2[i]; }
  }
  if (tid < 64){
    b1s[tid] = nb1_[l*64+tid]; b2s[tid] = nb2_[l*64+tid];
    lgs[tid] = lng_[l*64+tid]; lbs[tid] = lnb_[l*64+tid];
  }
  { // stage h row + agg sum
    float4 hv = *(const float4*)(h + row*64 + j0);
    *(float4*)(HR + rl*68 + j0) = hv;
    float4 s = {0.f,0.f,0.f,0.f};
    int i0 = ioff[n], i1 = ioff[n+1];
    for (int i = i0; i < i1; i++){
      float4 v = *(const float4*)(P + i*1024 + bb*64 + j0);
      s.x += v.x; s.y += v.y; s.z += v.z; s.w += v.w;
    }
    *(float4*)(AG + rl*68 + j0) = s;
  }
  __syncthreads();

  // phase 1: t = silu(hr@nW1lo + ag@nW1hi + nb1)
  float4 t = { b1s[j0], b1s[j0+1], b1s[j0+2], b1s[j0+3] };
  #pragma unroll 8
  for (int k = 0; k < 64; k++){
    float hk = HR[rl*68 + k], ak = AG[rl*68 + k];
    float4 w1 = *(const float4*)(W0 + k*64 + j0);
    float4 w2 = *(const float4*)(W1 + k*64 + j0);
    t.x += hk*w1.x + ak*w2.x; t.y += hk*w1.y + ak*w2.y;
    t.z += hk*w1.z + ak*w2.z; t.w += hk*w1.w + ak*w2.w;
  }
  t.x = silu2(t.x); t.y = silu2(t.y); t.z = silu2(t.z); t.w = silu2(t.w);
  *(float4*)(TL + rl*68 + j0) = t;
  __syncthreads();

  { // restage W0 := nW2
    const float4* p3 = (const float4*)(nW2 + l*4096);
    for (int i = tid; i < 1024; i += 256) ((float4*)W0)[i] = p3[i];
  }
  __syncthreads();

  // phase 2: u = t@nW2 + nb2; hv = hr + u; LayerNorm
  float4 u = { b2s[j0], b2s[j0+1], b2s[j0+2], b2s[j0+3] };
  #pragma unroll 8
  for (int k = 0; k < 64; k++){
    float tk = TL[rl*68 + k];
    float4 w = *(const float4*)(W0 + k*64 + j0);
    u.x += tk*w.x; u.y += tk*w.y; u.z += tk*w.z; u.w += tk*w.w;
  }
  float4 hold = *(const float4*)(HR + rl*68 + j0);
  float4 hv = { hold.x + u.x, hold.y + u.y, hold.z + u.z, hold.w + u.w };
  float s1 = hv.x + hv.y + hv.z + hv.w;
  float s2 = hv.x*hv.x + hv.y*hv.y + hv.z*hv.z + hv.w*hv.w;
  s1 += __shfl_xor(s1, 1, 64); s1 += __shfl_xor(s1, 2, 64);
  s1 += __shfl_xor(s1, 4, 64); s1 += __shfl_xor(s1, 8, 64);
  s2 += __shfl_xor(s2, 1, 64); s2 += __shfl_xor(s2, 2, 64);
  s2 += __shfl_xor(s2, 4, 64); s2 += __shfl_xor(s2, 8, 64);
  float mu  = s1 * (1.0f/64.0f);
  float var = s2 * (1.0f/64.0f) - mu*mu;
  float rs  = rsqrtf(var + 1e-5f);
  float4 hn;
  hn.x = (hv.x-mu)*rs*lgs[j0+0] + lbs[j0+0];
  hn.y = (hv.y-mu)*rs*lgs[j0+1] + lbs[j0+1];
  hn.z = (hv.z-mu)*rs*lgs[j0+2] + lbs[j0+2];
  hn.w = (hv.w-mu)*rs*lgs[j0+3] + lbs[j0+3];
  if (!LAST) *(float4*)(h + row*64 + j0) = hn;
  *(float4*)(HR + rl*68 + j0) = hn;   // own cols only; phase-1 reads sync'd out
  __syncthreads();

  if (!LAST){
    { // restage W0/W1 := eW1(l+1) lo|hi
      const float4* e1a = (const float4*)(eW1 + (l+1)*8256);
      const float4* e1b = (const float4*)(eW1 + (l+1)*8256 + 4096);
      for (int i = tid; i < 1024; i += 256){ ((float4*)W0)[i] = e1a[i]; ((float4*)W1)[i] = e1b[i]; }
    }
    if (tid < 64) b1s[tid] = eb1_[(l+1)*64 + tid];
    __syncthreads();
    float4 a1 = { b1s[j0], b1s[j0+1], b1s[j0+2], b1s[j0+3] };
    float4 a2 = { 0.f, 0.f, 0.f, 0.f };
    #pragma unroll 8
    for (int k = 0; k < 64; k++){
      float hk = HR[rl*68 + k];
      float4 w1 = *(const float4*)(W0 + k*64 + j0);
      float4 w2 = *(const float4*)(W1 + k*64 + j0);
      a1.x += hk*w1.x; a1.y += hk*w1.y; a1.z += hk*w1.z; a1.w += hk*w1.w;
      a2.x += hk*w2.x; a2.y += hk*w2.y; a2.z += hk*w2.z; a2.w += hk*w2.w;
    }
    int tb = (n*16 + bb)*64;
    *(float4*)(A1t + tb + j0) = a1;
    uint2 pk; pk.x = packbf(a2.x, a2.y); pk.y = packbf(a2.z, a2.w);
    *(uint2*)(A2bf + tb + j0) = pk;
  } else {
    { // restage W0 := oW1
      const float4* w1p = (const float4*)oW1;
      for (int i = tid; i < 1024; i += 256) ((float4*)W0)[i] = w1p[i];
    }
    if (tid < 192) W2o[tid] = oW2[tid];
    if (tid < 64)  b1s[tid] = ob1_[tid];
    if (tid < 3)   ob2s[tid] = ob2_[tid];
    __syncthreads();
    float4 tr = { b1s[j0], b1s[j0+1], b1s[j0+2], b1s[j0+3] };
    #pragma unroll 8
    for (int k = 0; k < 64; k++){
      float hk = HR[rl*68 + k];
      float4 w = *(const float4*)(W0 + k*64 + j0);
      tr.x += hk*w.x; tr.y += hk*w.y; tr.z += hk*w.z; tr.w += hk*w.w;
    }
    float4 t4 = { fmaxf(tr.x,0.f), fmaxf(tr.y,0.f), fmaxf(tr.z,0.f), fmaxf(tr.w,0.f) };
    *(float4*)(TL + rl*68 + j0) = t4;
    __syncthreads();
    if (c < 3){
      float acc = ob2s[c];
      #pragma unroll 8
      for (int k = 0; k < 64; k++) acc += TL[rl*68 + k] * W2o[k*3 + c];
      out[bb*3072 + n*3 + c] = acc;
    }
  }
}

} // namespace

extern "C" void kernel_launch(void* const* d_in, const int* in_sizes, int n_in,
                              void* d_out, int out_size, void* d_ws, size_t ws_size,
                              hipStream_t stream){
  const float* z   = (const float*)d_in[0];
  const int*   ei  = (const int*)d_in[1];
  const float* nf  = (const float*)d_in[2];
  const float* Wg  = (const float*)d_in[3];  const float* bg  = (const float*)d_in[4];
  const float* Wn  = (const float*)d_in[5];  const float* bn  = (const float*)d_in[6];
  const float* eW1 = (const float*)d_in[7];  const float* eb1 = (const float*)d_in[8];
  const float* eW2 = (const float*)d_in[9];  const float* eb2 = (const float*)d_in[10];
  const float* nW1 = (const float*)d_in[14]; const float* nb1 = (const float*)d_in[15];
  const float* nW2 = (const float*)d_in[16]; const float* nb2 = (const float*)d_in[17];
  const float* lng = (const float*)d_in[18]; const float* lnb = (const float*)d_in[19];
  const float* oW1 = (const float*)d_in[20]; const float* ob1 = (const float*)d_in[21];
  const float* oW2 = (const float*)d_in[22]; const float* ob2 = (const float*)d_in[23];

  float* W      = (float*)d_ws;
  float* h      = W;                                   // 1,048,576 f
  float* A1t    = W + 1048576;                         // 1,048,576 f
  unsigned short* A2bf   = (unsigned short*)(W + 2097152); // 1,048,576 bf16
  unsigned short* wfragE = (unsigned short*)(W + 2621440); // 16,384 bf16
  float* P      = W + 2629632;                         // 2560*1024 f
  float* g      = W + 5251072;                         // 1024 f
  int*   cntI   = (int*)(W + 5252096);                 // 1024
  int*   off    = cntI + 1024;                         // 1025
  int*   ioff   = off + 1025;                          // 1025
  int*   fill   = ioff + 1025;                         // 1024
  int*   items  = fill + 1024;                         // 2560
  int*   nitems = items + 2560;                        // 1
  int*   ecol   = nitems + 1;                          // 32768

  hipMemsetAsync(cntI, 0, 1024*sizeof(int), stream);
  k_count <<<128, 256, 0, stream>>>(ei, cntI);
  k_scan  <<<1,  1024, 0, stream>>>(cntI, off, ioff, fill, items, nitems);
  k_bucket<<<128, 256, 0, stream>>>(ei, off, fill, ecol, eW2, wfragE, z, Wg, bg, g);
  k_pre   <<<1024, 256, 0, stream>>>(nf, Wn, bn, g, eW1, eb1, h, A1t, A2bf);

  for (int l = 0; l < 4; l++){
    k_edge<<<640, 256, 0, stream>>>(A1t, A2bf, wfragE, eb2, l, off, ecol,
                                    items, nitems, P);
    if (l < 3)
      k_post<false><<<1024, 256, 0, stream>>>(l, h, P, ioff, nW1, nb1, nW2, nb2,
            lng, lnb, eW1, eb1, A1t, A2bf, oW1, ob1, oW2, ob2, (float*)d_out);
    else
      k_post<true> <<<1024, 256, 0, stream>>>(l, h, P, ioff, nW1, nb1, nW2, nb2,
            lng, lnb, eW1, eb1, A1t, A2bf, oW1, ob1, oW2, ob2, (float*)d_out);
  }
}